// Round 12
// baseline (363.028 us; speedup 1.0000x reference)
//
#include <hip/hip_runtime.h>

typedef unsigned short u16;

#define M_ROWS 8192
#define N_ROWS 16384
#define KDIM   512
#define BM     256
#define BN     128
#define BK     64
#define NCHUNKS 16
#define NPER   (N_ROWS / NCHUNKS)   /* 1024 */
#define TOPK   9

typedef __attribute__((ext_vector_type(8)))  short bf16x8;
typedef __attribute__((ext_vector_type(16))) float f32x16;

__device__ __forceinline__ void gload_lds16(const void* g, void* l) {
  __builtin_amdgcn_global_load_lds(
      (const __attribute__((address_space(1))) void*)g,
      (__attribute__((address_space(3))) void*)l,
      16, 0, 0);
}

__device__ __forceinline__ u16 f2bf(float x) {
  union { float f; unsigned u; } c; c.f = x;
  unsigned u = c.u;
  u += 0x7fffu + ((u >> 16) & 1u);   // RNE; inputs finite randn
  return (u16)(u >> 16);
}

__device__ __forceinline__ void topk_update(float v, float* best) {
  if (v < best[TOPK - 1]) {
    #pragma unroll
    for (int i = 0; i < TOPK; ++i) {
      float b = best[i];
      best[i] = fminf(b, v);
      v = fmaxf(b, v);
    }
  }
}

// ---- Kernel 1: fp32 -> bf16 convert + fp32 row norms; mb norms scattered into
//      MFMA-C-layout permuted order so the GEMM epilogue reads them as broadcasts.
//      Also zeroes the last-finisher counters (stream-ordered before the GEMM).
__global__ __launch_bounds__(256) void prep_kernel(
    const float* __restrict__ fv, const float* __restrict__ mb,
    u16* __restrict__ fvb, u16* __restrict__ mbb,
    float* __restrict__ nf, float* __restrict__ nm_perm, int* __restrict__ cnt)
{
  if (blockIdx.x == 0 && threadIdx.x < 32) cnt[threadIdx.x] = 0;
  int idx = blockIdx.x * 4 + (threadIdx.x >> 6);   // one wave per row
  int l = threadIdx.x & 63;
  const float* src; u16* dst;
  if (idx < M_ROWS) {
    src = fv + (size_t)idx * KDIM; dst = fvb + (size_t)idx * KDIM;
  } else {
    int r = idx - M_ROWS;
    src = mb + (size_t)r * KDIM; dst = mbb + (size_t)r * KDIM;
  }
  float4 x0 = ((const float4*)src)[2 * l];
  float4 x1 = ((const float4*)src)[2 * l + 1];
  float s = x0.x * x0.x + x0.y * x0.y + x0.z * x0.z + x0.w * x0.w
          + x1.x * x1.x + x1.y * x1.y + x1.z * x1.z + x1.w * x1.w;
  uint4 o;
  o.x = (unsigned)f2bf(x0.x) | ((unsigned)f2bf(x0.y) << 16);
  o.y = (unsigned)f2bf(x0.z) | ((unsigned)f2bf(x0.w) << 16);
  o.z = (unsigned)f2bf(x1.x) | ((unsigned)f2bf(x1.y) << 16);
  o.w = (unsigned)f2bf(x1.z) | ((unsigned)f2bf(x1.w) << 16);
  ((uint4*)dst)[l] = o;
  #pragma unroll
  for (int off = 32; off > 0; off >>= 1) s += __shfl_down(s, off, 64);
  if (l == 0) {
    if (idx < M_ROWS) {
      nf[idx] = s;
    } else {
      // 32x32 C/D: within-tile row w5 = (r&3) + 8*(r>>2) + 4*h  ->  [tile][h][r]
      int n  = idx - M_ROWS;
      int ig = n >> 5;            // global 32-row tile index (512 tiles)
      int w5 = n & 31;
      int h  = (w5 >> 2) & 1;
      int r  = (w5 & 3) | ((w5 >> 3) << 2);
      nm_perm[(ig * 2 + h) * 16 + r] = s;
    }
  }
}

// ---- Kernel 2: bf16 32x32x16 MFMA GEMM (swapped operands) + per-thread top-9
//      + FUSED per-row merge (last-finisher block per m-group). K-loop = R9's
//      proven structure, byte-identical (plateau note: 11 schedule variants over
//      R0-R11 span 219-280 us; this 2-phase 2-blocks/CU config is the floor).
// R12 change: after writing its sorted partial lists, each block does
// __threadfence (release) + atomicAdd(cnt[bx]); the 16th finisher acquires
// (__threadfence: inv L2, also kills cross-iteration stale lines) and merges
// all 16 lists for its 256 rows (1 thread/row, early-break), writing final9 +
// out_pix, then resets cnt. Eliminates the merge dispatch (~3 us + ~12 us gap).
__global__ __launch_bounds__(256, 2) void gemm_topk_kernel(
    const u16* __restrict__ fvb, const u16* __restrict__ mbb,
    const float* __restrict__ nm_perm, float* __restrict__ partial,
    const float* __restrict__ nf, float* __restrict__ final9,
    float* __restrict__ out_pix, int* __restrict__ cnt)
{
  __shared__ __align__(16) u16 As[BM * BK];     // fv tile [256][64], 32 KB
  __shared__ __align__(16) u16 Bs[BN * BK];     // mb tile [128][64], 16 KB
  __shared__ int sLast;

  const int t   = threadIdx.x;
  const int l   = t & 63;
  const int w   = t >> 6;
  const int h   = l >> 5;        // half-wave
  const int c31 = l & 31;
  const int cx  = c31 & 7;       // frag-read row&7 (both As strips and Bs tiles)

  const int m0    = blockIdx.x * BM;
  const int ncoff = blockIdx.y * NPER;

  // staging: lane l covers row (base + l>>3), chunk l&7; source chunk swizzled
  const int srow_lo = l >> 3;                    // 0..7
  const int sc      = ((l & 7) ^ srow_lo) * 8;   // swizzled source k-offset (u16)

  float best[2][TOPK];
  float T[2];
  #pragma unroll
  for (int s = 0; s < 2; ++s) {
    T[s] = 3.4e38f;
    #pragma unroll
    for (int i = 0; i < TOPK; ++i) best[s][i] = 3.4e38f;
  }

  for (int nt = 0; nt < NPER / BN; ++nt) {
    const int nbase = ncoff + nt * BN;
    f32x16 acc[2][4];
    #pragma unroll
    for (int s = 0; s < 2; ++s)
      #pragma unroll
      for (int i = 0; i < 4; ++i)
        #pragma unroll
        for (int r = 0; r < 16; ++r) acc[s][i][r] = 0.0f;

    for (int kc = 0; kc < KDIM / BK; ++kc) {
      __syncthreads();
      const int kb = kc * BK + sc;
      #pragma unroll
      for (int i = 0; i < 8; ++i)
        gload_lds16(fvb + (size_t)(m0 + w * 64 + i * 8 + srow_lo) * KDIM + kb,
                    &As[(w * 64 + i * 8) * BK]);
      #pragma unroll
      for (int i = 0; i < 4; ++i)
        gload_lds16(mbb + (size_t)(nbase + w * 32 + i * 8 + srow_lo) * KDIM + kb,
                    &Bs[(w * 32 + i * 8) * BK]);
      __syncthreads();
      #pragma unroll
      for (int kk = 0; kk < 4; ++kk) {
        const int ch = ((kk * 2 + h) ^ cx) * 8;              // swizzled chunk (u16)
        bf16x8 f0 = *(const bf16x8*)&As[(w * 64 +      c31) * BK + ch];  // B-op strip 0
        bf16x8 f1 = *(const bf16x8*)&As[(w * 64 + 32 + c31) * BK + ch];  // B-op strip 1
        #pragma unroll
        for (int i = 0; i < 4; ++i) {
          bf16x8 mbf = *(const bf16x8*)&Bs[(i * 32 + c31) * BK + ch]; // A-operand (n)
          acc[0][i] = __builtin_amdgcn_mfma_f32_32x32x16_bf16(mbf, f0, acc[0][i], 0, 0, 0);
          acc[1][i] = __builtin_amdgcn_mfma_f32_32x32x16_bf16(mbf, f1, acc[1][i], 0, 0, 0);
        }
      }
    }

    // ---- register epilogue: two lists per thread; nm in permuted broadcast order ----
    #pragma unroll
    for (int i = 0; i < 4; ++i) {
      const float4* np = (const float4*)&nm_perm[(((nbase >> 5) + i) * 2 + h) * 16];
      float4 q0 = np[0], q1 = np[1], q2 = np[2], q3 = np[3];
      #pragma unroll
      for (int s = 0; s < 2; ++s) {
        float v[16];
        v[ 0] = fmaf(-2.0f, acc[s][i][ 0], q0.x);
        v[ 1] = fmaf(-2.0f, acc[s][i][ 1], q0.y);
        v[ 2] = fmaf(-2.0f, acc[s][i][ 2], q0.z);
        v[ 3] = fmaf(-2.0f, acc[s][i][ 3], q0.w);
        v[ 4] = fmaf(-2.0f, acc[s][i][ 4], q1.x);
        v[ 5] = fmaf(-2.0f, acc[s][i][ 5], q1.y);
        v[ 6] = fmaf(-2.0f, acc[s][i][ 6], q1.z);
        v[ 7] = fmaf(-2.0f, acc[s][i][ 7], q1.w);
        v[ 8] = fmaf(-2.0f, acc[s][i][ 8], q2.x);
        v[ 9] = fmaf(-2.0f, acc[s][i][ 9], q2.y);
        v[10] = fmaf(-2.0f, acc[s][i][10], q2.z);
        v[11] = fmaf(-2.0f, acc[s][i][11], q2.w);
        v[12] = fmaf(-2.0f, acc[s][i][12], q3.x);
        v[13] = fmaf(-2.0f, acc[s][i][13], q3.y);
        v[14] = fmaf(-2.0f, acc[s][i][14], q3.z);
        v[15] = fmaf(-2.0f, acc[s][i][15], q3.w);
        float bmin = 3.4e38f;
        #pragma unroll
        for (int r = 0; r < 16; ++r) bmin = fminf(bmin, v[r]);
        if (bmin < T[s]) {
          #pragma unroll
          for (int r = 0; r < 16; ++r) topk_update(v[r], best[s]);
          T[s] = best[s][TOPK - 1];
        }
      }
    }
    #pragma unroll
    for (int s = 0; s < 2; ++s)
      T[s] = fminf(best[s][TOPK - 1], __shfl_xor(best[s][TOPK - 1], 32, 64));
  }

  // merge the lane pair sharing each m-col (snapshot partner list, then insert)
  #pragma unroll
  for (int s = 0; s < 2; ++s) {
    float tmp[TOPK];
    #pragma unroll
    for (int q = 0; q < TOPK; ++q) tmp[q] = __shfl_xor(best[s][q], 32, 64);
    #pragma unroll
    for (int q = 0; q < TOPK; ++q) topk_update(tmp[q], best[s]);
    int m = m0 + w * 64 + s * 32 + c31;
    size_t base = ((size_t)blockIdx.y * M_ROWS + m) * TOPK;
    if (h == 0) {
      #pragma unroll
      for (int q = 0; q < 5; ++q) partial[base + q] = best[s][q];
    } else {
      #pragma unroll
      for (int q = 5; q < TOPK; ++q) partial[base + q] = best[s][q];
    }
  }

  // ---- fused merge: last finisher of this m-group merges all 16 chunk lists ----
  __threadfence();                                    // release partial writes
  if (t == 0) sLast = (atomicAdd(&cnt[blockIdx.x], 1) == NCHUNKS - 1) ? 1 : 0;
  __syncthreads();
  if (sLast) {
    __threadfence();                                  // acquire: inv stale cache
    const int row = m0 + t;                           // 256 threads, 256 rows
    float fb[TOPK];
    #pragma unroll
    for (int i = 0; i < TOPK; ++i) fb[i] = 3.4e38f;
    for (int s = 0; s < NCHUNKS; ++s) {
      const float* p = &partial[((size_t)s * M_ROWS + row) * TOPK];
      #pragma unroll
      for (int i = 0; i < TOPK; ++i) {
        float pv = p[i];
        if (pv >= fb[TOPK - 1]) break;                // lists sorted ascending
        topk_update(pv, fb);
      }
    }
    float nfr = nf[row];
    float d0 = 0.0f;
    #pragma unroll
    for (int i = 0; i < TOPK; ++i) {
      float di = sqrtf(fmaxf(fb[i] + nfr, 0.0f));
      if (i == 0) d0 = di;
      final9[(size_t)row * TOPK + i] = di;
    }
    out_pix[row] = d0;
    if (t == 0) cnt[blockIdx.x] = 0;                  // self-clean for next iter
  }
}

// ---------------- Kernel 3: per-image argmax (first-max) + softmax score ----------------
__global__ __launch_bounds__(256) void img_kernel(
    const float* __restrict__ out_pix, const float* __restrict__ final9,
    const int* __restrict__ bptr, float* __restrict__ out_img)
{
  int img = blockIdx.x, t = threadIdx.x;
  float bv = -1.0f; int bi = 0;
  for (int p = t; p < 1024; p += 256) {
    float v = out_pix[img * 1024 + p];
    if (v > bv) { bv = v; bi = p; }
  }
  __shared__ float sv[256];
  __shared__ int   si[256];
  sv[t] = bv; si[t] = bi;
  __syncthreads();
  for (int off = 128; off > 0; off >>= 1) {
    if (t < off) {
      float v2 = sv[t + off]; int i2 = si[t + off];
      if (v2 > sv[t] || (v2 == sv[t] && i2 < si[t])) { sv[t] = v2; si[t] = i2; }
    }
    __syncthreads();
  }
  if (t == 0) {
    int row = img * 1024 + si[0];
    int b = bptr[0];
    float s0 = final9[(size_t)row * TOPK + 0];
    float score = s0;
    if (b > 1) {
      int bb = b < TOPK ? b : TOPK;
      float mx = s0;
      for (int i = 1; i < bb; ++i) mx = fmaxf(mx, final9[(size_t)row * TOPK + i]);
      float den = 0.0f;
      for (int i = 0; i < bb; ++i) den += expf(final9[(size_t)row * TOPK + i] - mx);
      score = s0 * (1.0f - expf(s0 - mx) / den);
    }
    out_img[img] = score;
  }
}

extern "C" void kernel_launch(void* const* d_in, const int* in_sizes, int n_in,
                              void* d_out, int out_size, void* d_ws, size_t ws_size,
                              hipStream_t stream) {
  const float* fv   = (const float*)d_in[0];
  const float* mb   = (const float*)d_in[1];
  const int*   bptr = (const int*)d_in[2];
  float* out = (float*)d_out;

  char* ws = (char*)d_ws;
  u16*   fvb     = (u16*)ws;                       // 8388608 B
  u16*   mbb     = (u16*)(ws + 8388608);           // 16777216 B
  float* nf      = (float*)(ws + 25165824);        // 32768 B
  float* nm_perm = (float*)(ws + 25198592);        // 65536 B
  float* partial = (float*)(ws + 25264128);        // 16*8192*9*4 = 4718592 B
  float* final9  = (float*)(ws + 29982720);        // 294912 B
  int*   cnt     = (int*)(ws + 30277632);          // 128 B (end ~30.3 MB)

  hipLaunchKernelGGL(prep_kernel, dim3((M_ROWS + N_ROWS) / 4), dim3(256), 0, stream,
                     fv, mb, fvb, mbb, nf, nm_perm, cnt);
  hipLaunchKernelGGL(gemm_topk_kernel, dim3(M_ROWS / BM, NCHUNKS), dim3(256), 0, stream,
                     fvb, mbb, nm_perm, partial, nf, final9, out, cnt);
  hipLaunchKernelGGL(img_kernel, dim3(8), dim3(256), 0, stream,
                     out, final9, bptr, out + M_ROWS);
}

// Round 14
// 298.853 us; speedup vs baseline: 1.2147x; 1.2147x over previous
//
#include <hip/hip_runtime.h>

typedef unsigned short u16;

#define M_ROWS 8192
#define N_ROWS 16384
#define KDIM   512
#define BM     256
#define BN     128
#define BK     64
#define NCHUNKS 16
#define NPER   (N_ROWS / NCHUNKS)   /* 1024 */
#define TOPK   9

typedef __attribute__((ext_vector_type(8)))  short bf16x8;
typedef __attribute__((ext_vector_type(16))) float f32x16;

__device__ __forceinline__ void gload_lds16(const void* g, void* l) {
  __builtin_amdgcn_global_load_lds(
      (const __attribute__((address_space(1))) void*)g,
      (__attribute__((address_space(3))) void*)l,
      16, 0, 0);
}

__device__ __forceinline__ u16 f2bf(float x) {
  union { float f; unsigned u; } c; c.f = x;
  unsigned u = c.u;
  u += 0x7fffu + ((u >> 16) & 1u);   // RNE; inputs finite randn
  return (u16)(u >> 16);
}

__device__ __forceinline__ void topk_update(float v, float* best) {
  if (v < best[TOPK - 1]) {
    #pragma unroll
    for (int i = 0; i < TOPK; ++i) {
      float b = best[i];
      best[i] = fminf(b, v);
      v = fmaxf(b, v);
    }
  }
}

// ---- Kernel 1: fp32 -> bf16 convert + fp32 row norms; mb norms scattered into
//      MFMA-C-layout permuted order so the GEMM epilogue reads them as broadcasts.
__global__ __launch_bounds__(256) void prep_kernel(
    const float* __restrict__ fv, const float* __restrict__ mb,
    u16* __restrict__ fvb, u16* __restrict__ mbb,
    float* __restrict__ nf, float* __restrict__ nm_perm)
{
  int idx = blockIdx.x * 4 + (threadIdx.x >> 6);   // one wave per row
  int l = threadIdx.x & 63;
  const float* src; u16* dst;
  if (idx < M_ROWS) {
    src = fv + (size_t)idx * KDIM; dst = fvb + (size_t)idx * KDIM;
  } else {
    int r = idx - M_ROWS;
    src = mb + (size_t)r * KDIM; dst = mbb + (size_t)r * KDIM;
  }
  float4 x0 = ((const float4*)src)[2 * l];
  float4 x1 = ((const float4*)src)[2 * l + 1];
  float s = x0.x * x0.x + x0.y * x0.y + x0.z * x0.z + x0.w * x0.w
          + x1.x * x1.x + x1.y * x1.y + x1.z * x1.z + x1.w * x1.w;
  uint4 o;
  o.x = (unsigned)f2bf(x0.x) | ((unsigned)f2bf(x0.y) << 16);
  o.y = (unsigned)f2bf(x0.z) | ((unsigned)f2bf(x0.w) << 16);
  o.z = (unsigned)f2bf(x1.x) | ((unsigned)f2bf(x1.y) << 16);
  o.w = (unsigned)f2bf(x1.z) | ((unsigned)f2bf(x1.w) << 16);
  ((uint4*)dst)[l] = o;
  #pragma unroll
  for (int off = 32; off > 0; off >>= 1) s += __shfl_down(s, off, 64);
  if (l == 0) {
    if (idx < M_ROWS) {
      nf[idx] = s;
    } else {
      // 32x32 C/D: within-tile row w5 = (r&3) + 8*(r>>2) + 4*h  ->  [tile][h][r]
      int n  = idx - M_ROWS;
      int ig = n >> 5;            // global 32-row tile index (512 tiles)
      int w5 = n & 31;
      int h  = (w5 >> 2) & 1;
      int r  = (w5 & 3) | ((w5 >> 3) << 2);
      nm_perm[(ig * 2 + h) * 16 + r] = s;
    }
  }
}

// ---- Kernel 2: bf16 32x32x16 MFMA GEMM (swapped operands) + per-thread top-9 ----
// grid (32, 16), block 256 (4 waves). Block: 256 fv-rows (m) x 1024 mb-rows (n).
// Wave owns a 64-wide m-strip (2 x 32 sub-strips): per kk 2 fvf + 4 mbf
// ds_read_b128 feed 8 MFMAs = 0.75 reads/MFMA. acc[2][4] = 128 AGPR.
// PLATEAU NOTE (R0-R13): 11 schedule variants (coarse/counted-vmcnt/fine-phase x
// 128^2/256x128/256^2 x 1-3 blocks/CU x 32x32/16x16 frags) all land 219-280 us,
// floor 219 = ~630 TF. Binding constraint: 128-AGPR acc -> 2 waves/SIMD -> 2
// blocks/CU; cross-dispatch fusion refuted (R12 fence L2-thrash -40%; R13 coop
// launch incompatible with graph capture). This config is the measured optimum.
// C[row=n][col=m]. Ranked v = nm[n] - 2*dot (nf[m] deferred to merge).
// LDS XOR-swizzle: 16B chunk c of row r stored at chunk c^(r&7); staging permutes
// the per-lane SOURCE k-offset (bijection per row), frag reads XOR the chunk.
__global__ __launch_bounds__(256, 2) void gemm_topk_kernel(
    const u16* __restrict__ fvb, const u16* __restrict__ mbb,
    const float* __restrict__ nm_perm, float* __restrict__ partial)
{
  __shared__ __align__(16) u16 As[BM * BK];     // fv tile [256][64], 32 KB
  __shared__ __align__(16) u16 Bs[BN * BK];     // mb tile [128][64], 16 KB

  const int t   = threadIdx.x;
  const int l   = t & 63;
  const int w   = t >> 6;
  const int h   = l >> 5;        // half-wave
  const int c31 = l & 31;
  const int cx  = c31 & 7;       // frag-read row&7 (both As strips and Bs tiles)

  const int m0    = blockIdx.x * BM;
  const int ncoff = blockIdx.y * NPER;

  // staging: lane l covers row (base + l>>3), chunk l&7; source chunk swizzled
  const int srow_lo = l >> 3;                    // 0..7
  const int sc      = ((l & 7) ^ srow_lo) * 8;   // swizzled source k-offset (u16)

  float best[2][TOPK];
  float T[2];
  #pragma unroll
  for (int s = 0; s < 2; ++s) {
    T[s] = 3.4e38f;
    #pragma unroll
    for (int i = 0; i < TOPK; ++i) best[s][i] = 3.4e38f;
  }

  for (int nt = 0; nt < NPER / BN; ++nt) {
    const int nbase = ncoff + nt * BN;
    f32x16 acc[2][4];
    #pragma unroll
    for (int s = 0; s < 2; ++s)
      #pragma unroll
      for (int i = 0; i < 4; ++i)
        #pragma unroll
        for (int r = 0; r < 16; ++r) acc[s][i][r] = 0.0f;

    for (int kc = 0; kc < KDIM / BK; ++kc) {
      __syncthreads();
      const int kb = kc * BK + sc;
      #pragma unroll
      for (int i = 0; i < 8; ++i)
        gload_lds16(fvb + (size_t)(m0 + w * 64 + i * 8 + srow_lo) * KDIM + kb,
                    &As[(w * 64 + i * 8) * BK]);
      #pragma unroll
      for (int i = 0; i < 4; ++i)
        gload_lds16(mbb + (size_t)(nbase + w * 32 + i * 8 + srow_lo) * KDIM + kb,
                    &Bs[(w * 32 + i * 8) * BK]);
      __syncthreads();
      #pragma unroll
      for (int kk = 0; kk < 4; ++kk) {
        const int ch = ((kk * 2 + h) ^ cx) * 8;              // swizzled chunk (u16)
        bf16x8 f0 = *(const bf16x8*)&As[(w * 64 +      c31) * BK + ch];  // B-op strip 0
        bf16x8 f1 = *(const bf16x8*)&As[(w * 64 + 32 + c31) * BK + ch];  // B-op strip 1
        #pragma unroll
        for (int i = 0; i < 4; ++i) {
          bf16x8 mbf = *(const bf16x8*)&Bs[(i * 32 + c31) * BK + ch]; // A-operand (n)
          acc[0][i] = __builtin_amdgcn_mfma_f32_32x32x16_bf16(mbf, f0, acc[0][i], 0, 0, 0);
          acc[1][i] = __builtin_amdgcn_mfma_f32_32x32x16_bf16(mbf, f1, acc[1][i], 0, 0, 0);
        }
      }
    }

    // ---- register epilogue: two lists per thread; nm in permuted broadcast order ----
    #pragma unroll
    for (int i = 0; i < 4; ++i) {
      const float4* np = (const float4*)&nm_perm[(((nbase >> 5) + i) * 2 + h) * 16];
      float4 q0 = np[0], q1 = np[1], q2 = np[2], q3 = np[3];
      #pragma unroll
      for (int s = 0; s < 2; ++s) {
        float v[16];
        v[ 0] = fmaf(-2.0f, acc[s][i][ 0], q0.x);
        v[ 1] = fmaf(-2.0f, acc[s][i][ 1], q0.y);
        v[ 2] = fmaf(-2.0f, acc[s][i][ 2], q0.z);
        v[ 3] = fmaf(-2.0f, acc[s][i][ 3], q0.w);
        v[ 4] = fmaf(-2.0f, acc[s][i][ 4], q1.x);
        v[ 5] = fmaf(-2.0f, acc[s][i][ 5], q1.y);
        v[ 6] = fmaf(-2.0f, acc[s][i][ 6], q1.z);
        v[ 7] = fmaf(-2.0f, acc[s][i][ 7], q1.w);
        v[ 8] = fmaf(-2.0f, acc[s][i][ 8], q2.x);
        v[ 9] = fmaf(-2.0f, acc[s][i][ 9], q2.y);
        v[10] = fmaf(-2.0f, acc[s][i][10], q2.z);
        v[11] = fmaf(-2.0f, acc[s][i][11], q2.w);
        v[12] = fmaf(-2.0f, acc[s][i][12], q3.x);
        v[13] = fmaf(-2.0f, acc[s][i][13], q3.y);
        v[14] = fmaf(-2.0f, acc[s][i][14], q3.z);
        v[15] = fmaf(-2.0f, acc[s][i][15], q3.w);
        float bmin = 3.4e38f;
        #pragma unroll
        for (int r = 0; r < 16; ++r) bmin = fminf(bmin, v[r]);
        if (bmin < T[s]) {
          #pragma unroll
          for (int r = 0; r < 16; ++r) topk_update(v[r], best[s]);
          T[s] = best[s][TOPK - 1];
        }
      }
    }
    #pragma unroll
    for (int s = 0; s < 2; ++s)
      T[s] = fminf(best[s][TOPK - 1], __shfl_xor(best[s][TOPK - 1], 32, 64));
  }

  // merge the lane pair sharing each m-col (snapshot partner list, then insert)
  #pragma unroll
  for (int s = 0; s < 2; ++s) {
    float tmp[TOPK];
    #pragma unroll
    for (int q = 0; q < TOPK; ++q) tmp[q] = __shfl_xor(best[s][q], 32, 64);
    #pragma unroll
    for (int q = 0; q < TOPK; ++q) topk_update(tmp[q], best[s]);
    int m = m0 + w * 64 + s * 32 + c31;
    size_t base = ((size_t)blockIdx.y * M_ROWS + m) * TOPK;
    if (h == 0) {
      #pragma unroll
      for (int q = 0; q < 5; ++q) partial[base + q] = best[s][q];
    } else {
      #pragma unroll
      for (int q = 5; q < TOPK; ++q) partial[base + q] = best[s][q];
    }
  }
}

// ---- Kernel 3: merge 16 partial lists/row, sqrt, pixel scores ----
// Parallelized (R9): 512 blocks x 64 thr: 4 threads per row (lane quarter l>>4
// merges 4 sorted chunk-lists with early-break), then 2-step shfl_xor butterfly
// (32,16) merges quarters in-register; quarter 0 writes sqrt'd list.
__global__ __launch_bounds__(64) void merge_kernel(
    const float* __restrict__ partial, const float* __restrict__ nf,
    float* __restrict__ final9, float* __restrict__ out_pix)
{
  const int l   = threadIdx.x;            // 0..63
  const int row = blockIdx.x * 16 + (l & 15);
  const int q4  = l >> 4;                 // chunk quarter 0..3
  float best[TOPK];
  #pragma unroll
  for (int i = 0; i < TOPK; ++i) best[i] = 3.4e38f;
  #pragma unroll
  for (int s = 0; s < 4; ++s) {
    const float* p = &partial[((size_t)(q4 * 4 + s) * M_ROWS + row) * TOPK];
    #pragma unroll
    for (int i = 0; i < TOPK; ++i) {
      float pv = p[i];
      if (pv >= best[TOPK - 1]) break;    // chunk lists are sorted ascending
      topk_update(pv, best);
    }
  }
  // butterfly merge across the 4 quarters sharing this row
  {
    float tmp[TOPK];
    #pragma unroll
    for (int q = 0; q < TOPK; ++q) tmp[q] = __shfl_xor(best[q], 32, 64);
    #pragma unroll
    for (int q = 0; q < TOPK; ++q) topk_update(tmp[q], best);
    #pragma unroll
    for (int q = 0; q < TOPK; ++q) tmp[q] = __shfl_xor(best[q], 16, 64);
    #pragma unroll
    for (int q = 0; q < TOPK; ++q) topk_update(tmp[q], best);
  }
  if (q4 == 0) {
    float nfr = nf[row];
    float d[TOPK];
    #pragma unroll
    for (int i = 0; i < TOPK; ++i) d[i] = sqrtf(fmaxf(best[i] + nfr, 0.0f));
    out_pix[row] = d[0];
    #pragma unroll
    for (int i = 0; i < TOPK; ++i) final9[(size_t)row * TOPK + i] = d[i];
  }
}

// ---------------- Kernel 4: per-image argmax (first-max) + softmax score ----------------
__global__ __launch_bounds__(256) void img_kernel(
    const float* __restrict__ out_pix, const float* __restrict__ final9,
    const int* __restrict__ bptr, float* __restrict__ out_img)
{
  int img = blockIdx.x, t = threadIdx.x;
  float bv = -1.0f; int bi = 0;
  for (int p = t; p < 1024; p += 256) {
    float v = out_pix[img * 1024 + p];
    if (v > bv) { bv = v; bi = p; }
  }
  __shared__ float sv[256];
  __shared__ int   si[256];
  sv[t] = bv; si[t] = bi;
  __syncthreads();
  for (int off = 128; off > 0; off >>= 1) {
    if (t < off) {
      float v2 = sv[t + off]; int i2 = si[t + off];
      if (v2 > sv[t] || (v2 == sv[t] && i2 < si[t])) { sv[t] = v2; si[t] = i2; }
    }
    __syncthreads();
  }
  if (t == 0) {
    int row = img * 1024 + si[0];
    int b = bptr[0];
    float s0 = final9[(size_t)row * TOPK + 0];
    float score = s0;
    if (b > 1) {
      int bb = b < TOPK ? b : TOPK;
      float mx = s0;
      for (int i = 1; i < bb; ++i) mx = fmaxf(mx, final9[(size_t)row * TOPK + i]);
      float den = 0.0f;
      for (int i = 0; i < bb; ++i) den += expf(final9[(size_t)row * TOPK + i] - mx);
      score = s0 * (1.0f - expf(s0 - mx) / den);
    }
    out_img[img] = score;
  }
}

extern "C" void kernel_launch(void* const* d_in, const int* in_sizes, int n_in,
                              void* d_out, int out_size, void* d_ws, size_t ws_size,
                              hipStream_t stream) {
  const float* fv   = (const float*)d_in[0];
  const float* mb   = (const float*)d_in[1];
  const int*   bptr = (const int*)d_in[2];
  float* out = (float*)d_out;

  char* ws = (char*)d_ws;
  u16*   fvb     = (u16*)ws;                       // 8388608 B
  u16*   mbb     = (u16*)(ws + 8388608);           // 16777216 B
  float* nf      = (float*)(ws + 25165824);        // 32768 B
  float* nm_perm = (float*)(ws + 25198592);        // 65536 B
  float* partial = (float*)(ws + 25264128);        // 16*8192*9*4 = 4718592 B
  float* final9  = (float*)(ws + 29982720);        // 294912 B   (end ~30.3 MB)

  hipLaunchKernelGGL(prep_kernel, dim3((M_ROWS + N_ROWS) / 4), dim3(256), 0, stream,
                     fv, mb, fvb, mbb, nf, nm_perm);
  hipLaunchKernelGGL(gemm_topk_kernel, dim3(M_ROWS / BM, NCHUNKS), dim3(256), 0, stream,
                     fvb, mbb, nm_perm, partial);
  hipLaunchKernelGGL(merge_kernel, dim3(M_ROWS / 16), dim3(64), 0, stream,
                     partial, nf, final9, out);
  hipLaunchKernelGGL(img_kernel, dim3(8), dim3(256), 0, stream,
                     out, final9, bptr, out + M_ROWS);
}

// Round 15
// 288.584 us; speedup vs baseline: 1.2580x; 1.0356x over previous
//
#include <hip/hip_runtime.h>

typedef unsigned short u16;

#define M_ROWS 8192
#define N_ROWS 16384
#define KDIM   512
#define BM     256
#define BN     128
#define BK     64
#define NCHUNKS 16
#define NPER   (N_ROWS / NCHUNKS)   /* 1024 */
#define TOPK   9

typedef __attribute__((ext_vector_type(8)))  short bf16x8;
typedef __attribute__((ext_vector_type(16))) float f32x16;

__device__ __forceinline__ void gload_lds16(const void* g, void* l) {
  __builtin_amdgcn_global_load_lds(
      (const __attribute__((address_space(1))) void*)g,
      (__attribute__((address_space(3))) void*)l,
      16, 0, 0);
}

__device__ __forceinline__ u16 f2bf(float x) {
  union { float f; unsigned u; } c; c.f = x;
  unsigned u = c.u;
  u += 0x7fffu + ((u >> 16) & 1u);   // RNE; inputs finite randn
  return (u16)(u >> 16);
}

__device__ __forceinline__ void topk_update(float v, float* best) {
  if (v < best[TOPK - 1]) {
    #pragma unroll
    for (int i = 0; i < TOPK; ++i) {
      float b = best[i];
      best[i] = fminf(b, v);
      v = fmaxf(b, v);
    }
  }
}

// ---- Kernel 1: fp32 -> bf16 convert + fp32 row norms; mb norms scattered into
//      MFMA-C-layout permuted order so the GEMM epilogue reads them as broadcasts.
__global__ __launch_bounds__(256) void prep_kernel(
    const float* __restrict__ fv, const float* __restrict__ mb,
    u16* __restrict__ fvb, u16* __restrict__ mbb,
    float* __restrict__ nf, float* __restrict__ nm_perm)
{
  int idx = blockIdx.x * 4 + (threadIdx.x >> 6);   // one wave per row
  int l = threadIdx.x & 63;
  const float* src; u16* dst;
  if (idx < M_ROWS) {
    src = fv + (size_t)idx * KDIM; dst = fvb + (size_t)idx * KDIM;
  } else {
    int r = idx - M_ROWS;
    src = mb + (size_t)r * KDIM; dst = mbb + (size_t)r * KDIM;
  }
  float4 x0 = ((const float4*)src)[2 * l];
  float4 x1 = ((const float4*)src)[2 * l + 1];
  float s = x0.x * x0.x + x0.y * x0.y + x0.z * x0.z + x0.w * x0.w
          + x1.x * x1.x + x1.y * x1.y + x1.z * x1.z + x1.w * x1.w;
  uint4 o;
  o.x = (unsigned)f2bf(x0.x) | ((unsigned)f2bf(x0.y) << 16);
  o.y = (unsigned)f2bf(x0.z) | ((unsigned)f2bf(x0.w) << 16);
  o.z = (unsigned)f2bf(x1.x) | ((unsigned)f2bf(x1.y) << 16);
  o.w = (unsigned)f2bf(x1.z) | ((unsigned)f2bf(x1.w) << 16);
  ((uint4*)dst)[l] = o;
  #pragma unroll
  for (int off = 32; off > 0; off >>= 1) s += __shfl_down(s, off, 64);
  if (l == 0) {
    if (idx < M_ROWS) {
      nf[idx] = s;
    } else {
      // 32x32 C/D: within-tile row w5 = (r&3) + 8*(r>>2) + 4*h  ->  [tile][h][r]
      int n  = idx - M_ROWS;
      int ig = n >> 5;            // global 32-row tile index (512 tiles)
      int w5 = n & 31;
      int h  = (w5 >> 2) & 1;
      int r  = (w5 & 3) | ((w5 >> 3) << 2);
      nm_perm[(ig * 2 + h) * 16 + r] = s;
    }
  }
}

// ---- Kernel 2: bf16 32x32x16 MFMA GEMM (swapped operands) + per-thread top-9 ----
// grid (32, 16), block 256 (4 waves). Block: 256 fv-rows (m) x 1024 mb-rows (n).
// Wave owns a 64-wide m-strip; per kk 2 fvf + 4 mbf ds_read_b128 feed 8 MFMAs
// = 0.75 reads/MFMA. acc[2][4] = 128 AGPR. (Structural plateau note: R0-R13.)
// R15 change (HK technique 5 / SGPR address hoist): staging source address split
// into [scalar: base + (m0+wu*64+i*8)*KDIM + kb, wu=readfirstlane(w)] + [per-lane
// loop-invariant: srow_lo*KDIM + sc]. The scalar part compiles to SALU/SGPR
// (saddr-form global_load_lds); the per-lane part is ONE reused VGPR. R14 cycle
// accounting: VALUBusy 46% - MFMA 27% = 19% (~100K cyc) unexplained except by
// per-lane 64-bit addr mads per staging instr per kc (m98: 21 v_lshl_add_u64/
// K-iter in this kernel family). LDS dests use wu (m104 wave-uniform req).
// C[row=n][col=m]. Ranked v = nm[n] - 2*dot (nf[m] deferred to merge).
// LDS XOR-swizzle: 16B chunk c of row r stored at chunk c^(r&7); staging permutes
// the per-lane SOURCE k-offset (bijection per row), frag reads XOR the chunk.
__global__ __launch_bounds__(256, 2) void gemm_topk_kernel(
    const u16* __restrict__ fvb, const u16* __restrict__ mbb,
    const float* __restrict__ nm_perm, float* __restrict__ partial)
{
  __shared__ __align__(16) u16 As[BM * BK];     // fv tile [256][64], 32 KB
  __shared__ __align__(16) u16 Bs[BN * BK];     // mb tile [128][64], 16 KB

  const int t   = threadIdx.x;
  const int l   = t & 63;
  const int w   = t >> 6;
  const int wu  = __builtin_amdgcn_readfirstlane(w);   // wave-uniform, SGPR
  const int h   = l >> 5;        // half-wave
  const int c31 = l & 31;
  const int cx  = c31 & 7;       // frag-read row&7 (both As strips and Bs tiles)

  const int m0    = blockIdx.x * BM;
  const int ncoff = blockIdx.y * NPER;

  // staging: lane l covers row (base + l>>3), chunk l&7; source chunk swizzled
  const int srow_lo = l >> 3;                    // 0..7
  const int sc      = ((l & 7) ^ srow_lo) * 8;   // swizzled source k-offset (u16)
  const int laneA   = srow_lo * KDIM + sc;       // per-lane, loop-invariant

  // wave-uniform (scalar) staging bases
  const u16* aBase0 = fvb + (size_t)(m0 + wu * 64) * KDIM;
  const u16* bBase0 = mbb + (size_t)(ncoff + wu * 32) * KDIM;

  float best[2][TOPK];
  float T[2];
  #pragma unroll
  for (int s = 0; s < 2; ++s) {
    T[s] = 3.4e38f;
    #pragma unroll
    for (int i = 0; i < TOPK; ++i) best[s][i] = 3.4e38f;
  }

  for (int nt = 0; nt < NPER / BN; ++nt) {
    const int nbase = ncoff + nt * BN;
    const u16* bBaseNt = bBase0 + (size_t)nt * BN * KDIM;   // scalar
    f32x16 acc[2][4];
    #pragma unroll
    for (int s = 0; s < 2; ++s)
      #pragma unroll
      for (int i = 0; i < 4; ++i)
        #pragma unroll
        for (int r = 0; r < 16; ++r) acc[s][i][r] = 0.0f;

    for (int kc = 0; kc < KDIM / BK; ++kc) {
      __syncthreads();
      const u16* aS = aBase0 + kc * BK;       // scalar
      const u16* bS = bBaseNt + kc * BK;      // scalar
      #pragma unroll
      for (int i = 0; i < 8; ++i)
        gload_lds16(aS + (size_t)(i * 8) * KDIM + laneA,
                    &As[(wu * 64 + i * 8) * BK]);
      #pragma unroll
      for (int i = 0; i < 4; ++i)
        gload_lds16(bS + (size_t)(i * 8) * KDIM + laneA,
                    &Bs[(wu * 32 + i * 8) * BK]);
      __syncthreads();
      #pragma unroll
      for (int kk = 0; kk < 4; ++kk) {
        const int ch = ((kk * 2 + h) ^ cx) * 8;              // swizzled chunk (u16)
        bf16x8 f0 = *(const bf16x8*)&As[(wu * 64 +      c31) * BK + ch];  // B-op strip 0
        bf16x8 f1 = *(const bf16x8*)&As[(wu * 64 + 32 + c31) * BK + ch];  // B-op strip 1
        #pragma unroll
        for (int i = 0; i < 4; ++i) {
          bf16x8 mbf = *(const bf16x8*)&Bs[(i * 32 + c31) * BK + ch]; // A-operand (n)
          acc[0][i] = __builtin_amdgcn_mfma_f32_32x32x16_bf16(mbf, f0, acc[0][i], 0, 0, 0);
          acc[1][i] = __builtin_amdgcn_mfma_f32_32x32x16_bf16(mbf, f1, acc[1][i], 0, 0, 0);
        }
      }
    }

    // ---- register epilogue: two lists per thread; nm in permuted broadcast order ----
    #pragma unroll
    for (int i = 0; i < 4; ++i) {
      const float4* np = (const float4*)&nm_perm[(((nbase >> 5) + i) * 2 + h) * 16];
      float4 q0 = np[0], q1 = np[1], q2 = np[2], q3 = np[3];
      #pragma unroll
      for (int s = 0; s < 2; ++s) {
        float v[16];
        v[ 0] = fmaf(-2.0f, acc[s][i][ 0], q0.x);
        v[ 1] = fmaf(-2.0f, acc[s][i][ 1], q0.y);
        v[ 2] = fmaf(-2.0f, acc[s][i][ 2], q0.z);
        v[ 3] = fmaf(-2.0f, acc[s][i][ 3], q0.w);
        v[ 4] = fmaf(-2.0f, acc[s][i][ 4], q1.x);
        v[ 5] = fmaf(-2.0f, acc[s][i][ 5], q1.y);
        v[ 6] = fmaf(-2.0f, acc[s][i][ 6], q1.z);
        v[ 7] = fmaf(-2.0f, acc[s][i][ 7], q1.w);
        v[ 8] = fmaf(-2.0f, acc[s][i][ 8], q2.x);
        v[ 9] = fmaf(-2.0f, acc[s][i][ 9], q2.y);
        v[10] = fmaf(-2.0f, acc[s][i][10], q2.z);
        v[11] = fmaf(-2.0f, acc[s][i][11], q2.w);
        v[12] = fmaf(-2.0f, acc[s][i][12], q3.x);
        v[13] = fmaf(-2.0f, acc[s][i][13], q3.y);
        v[14] = fmaf(-2.0f, acc[s][i][14], q3.z);
        v[15] = fmaf(-2.0f, acc[s][i][15], q3.w);
        float bmin = 3.4e38f;
        #pragma unroll
        for (int r = 0; r < 16; ++r) bmin = fminf(bmin, v[r]);
        if (bmin < T[s]) {
          #pragma unroll
          for (int r = 0; r < 16; ++r) topk_update(v[r], best[s]);
          T[s] = best[s][TOPK - 1];
        }
      }
    }
    #pragma unroll
    for (int s = 0; s < 2; ++s)
      T[s] = fminf(best[s][TOPK - 1], __shfl_xor(best[s][TOPK - 1], 32, 64));
  }

  // merge the lane pair sharing each m-col (snapshot partner list, then insert)
  #pragma unroll
  for (int s = 0; s < 2; ++s) {
    float tmp[TOPK];
    #pragma unroll
    for (int q = 0; q < TOPK; ++q) tmp[q] = __shfl_xor(best[s][q], 32, 64);
    #pragma unroll
    for (int q = 0; q < TOPK; ++q) topk_update(tmp[q], best[s]);
    int m = m0 + wu * 64 + s * 32 + c31;
    size_t base = ((size_t)blockIdx.y * M_ROWS + m) * TOPK;
    if (h == 0) {
      #pragma unroll
      for (int q = 0; q < 5; ++q) partial[base + q] = best[s][q];
    } else {
      #pragma unroll
      for (int q = 5; q < TOPK; ++q) partial[base + q] = best[s][q];
    }
  }
}

// ---- Kernel 3: merge 16 partial lists/row, sqrt, pixel scores ----
// Parallelized (R9): 512 blocks x 64 thr: 4 threads per row (lane quarter l>>4
// merges 4 sorted chunk-lists with early-break), then 2-step shfl_xor butterfly
// (32,16) merges quarters in-register; quarter 0 writes sqrt'd list.
__global__ __launch_bounds__(64) void merge_kernel(
    const float* __restrict__ partial, const float* __restrict__ nf,
    float* __restrict__ final9, float* __restrict__ out_pix)
{
  const int l   = threadIdx.x;            // 0..63
  const int row = blockIdx.x * 16 + (l & 15);
  const int q4  = l >> 4;                 // chunk quarter 0..3
  float best[TOPK];
  #pragma unroll
  for (int i = 0; i < TOPK; ++i) best[i] = 3.4e38f;
  #pragma unroll
  for (int s = 0; s < 4; ++s) {
    const float* p = &partial[((size_t)(q4 * 4 + s) * M_ROWS + row) * TOPK];
    #pragma unroll
    for (int i = 0; i < TOPK; ++i) {
      float pv = p[i];
      if (pv >= best[TOPK - 1]) break;    // chunk lists are sorted ascending
      topk_update(pv, best);
    }
  }
  // butterfly merge across the 4 quarters sharing this row
  {
    float tmp[TOPK];
    #pragma unroll
    for (int q = 0; q < TOPK; ++q) tmp[q] = __shfl_xor(best[q], 32, 64);
    #pragma unroll
    for (int q = 0; q < TOPK; ++q) topk_update(tmp[q], best);
    #pragma unroll
    for (int q = 0; q < TOPK; ++q) tmp[q] = __shfl_xor(best[q], 16, 64);
    #pragma unroll
    for (int q = 0; q < TOPK; ++q) topk_update(tmp[q], best);
  }
  if (q4 == 0) {
    float nfr = nf[row];
    float d[TOPK];
    #pragma unroll
    for (int i = 0; i < TOPK; ++i) d[i] = sqrtf(fmaxf(best[i] + nfr, 0.0f));
    out_pix[row] = d[0];
    #pragma unroll
    for (int i = 0; i < TOPK; ++i) final9[(size_t)row * TOPK + i] = d[i];
  }
}

// ---------------- Kernel 4: per-image argmax (first-max) + softmax score ----------------
__global__ __launch_bounds__(256) void img_kernel(
    const float* __restrict__ out_pix, const float* __restrict__ final9,
    const int* __restrict__ bptr, float* __restrict__ out_img)
{
  int img = blockIdx.x, t = threadIdx.x;
  float bv = -1.0f; int bi = 0;
  for (int p = t; p < 1024; p += 256) {
    float v = out_pix[img * 1024 + p];
    if (v > bv) { bv = v; bi = p; }
  }
  __shared__ float sv[256];
  __shared__ int   si[256];
  sv[t] = bv; si[t] = bi;
  __syncthreads();
  for (int off = 128; off > 0; off >>= 1) {
    if (t < off) {
      float v2 = sv[t + off]; int i2 = si[t + off];
      if (v2 > sv[t] || (v2 == sv[t] && i2 < si[t])) { sv[t] = v2; si[t] = i2; }
    }
    __syncthreads();
  }
  if (t == 0) {
    int row = img * 1024 + si[0];
    int b = bptr[0];
    float s0 = final9[(size_t)row * TOPK + 0];
    float score = s0;
    if (b > 1) {
      int bb = b < TOPK ? b : TOPK;
      float mx = s0;
      for (int i = 1; i < bb; ++i) mx = fmaxf(mx, final9[(size_t)row * TOPK + i]);
      float den = 0.0f;
      for (int i = 0; i < bb; ++i) den += expf(final9[(size_t)row * TOPK + i] - mx);
      score = s0 * (1.0f - expf(s0 - mx) / den);
    }
    out_img[img] = score;
  }
}

extern "C" void kernel_launch(void* const* d_in, const int* in_sizes, int n_in,
                              void* d_out, int out_size, void* d_ws, size_t ws_size,
                              hipStream_t stream) {
  const float* fv   = (const float*)d_in[0];
  const float* mb   = (const float*)d_in[1];
  const int*   bptr = (const int*)d_in[2];
  float* out = (float*)d_out;

  char* ws = (char*)d_ws;
  u16*   fvb     = (u16*)ws;                       // 8388608 B
  u16*   mbb     = (u16*)(ws + 8388608);           // 16777216 B
  float* nf      = (float*)(ws + 25165824);        // 32768 B
  float* nm_perm = (float*)(ws + 25198592);        // 65536 B
  float* partial = (float*)(ws + 25264128);        // 16*8192*9*4 = 4718592 B
  float* final9  = (float*)(ws + 29982720);        // 294912 B   (end ~30.3 MB)

  hipLaunchKernelGGL(prep_kernel, dim3((M_ROWS + N_ROWS) / 4), dim3(256), 0, stream,
                     fv, mb, fvb, mbb, nf, nm_perm);
  hipLaunchKernelGGL(gemm_topk_kernel, dim3(M_ROWS / BM, NCHUNKS), dim3(256), 0, stream,
                     fvb, mbb, nm_perm, partial);
  hipLaunchKernelGGL(merge_kernel, dim3(M_ROWS / 16), dim3(64), 0, stream,
                     partial, nf, final9, out);
  hipLaunchKernelGGL(img_kernel, dim3(8), dim3(256), 0, stream,
                     out, final9, bptr, out + M_ROWS);
}